// Round 1
// baseline (14273.682 us; speedup 1.0000x reference)
//
#include <hip/hip_runtime.h>
#include <cstdint>
#include <cmath>

// ---------------- fp32 tiled GEMM: C = A @ B (+bias, optional per-row scaling) ----
// A: M x K row-major.  B: TRANSB ? (N x K) : (K x N) row-major.
// batched via blockIdx.z with element strides sA, sB, sC.
// rsA/rsB: optional per-row scale factors (used for cosine-sim normalization).
#define GBM 128
#define GBN 128
#define GBK 16

template<bool TRANSB>
__global__ __launch_bounds__(256)
void gemm_f32(int M, int N, int K,
              const float* __restrict__ A, long long sA,
              const float* __restrict__ B, long long sB,
              float* __restrict__ Cc, long long sC,
              const float* __restrict__ bias,
              const float* __restrict__ rsA,
              const float* __restrict__ rsB)
{
    const int z = blockIdx.z;
    A  += (size_t)z * (size_t)sA;
    B  += (size_t)z * (size_t)sB;
    Cc += (size_t)z * (size_t)sC;

    const int bm = blockIdx.y * GBM;
    const int bn = blockIdx.x * GBN;
    const int tid = threadIdx.x;
    const int tx = tid & 15;
    const int ty = tid >> 4;

    __shared__ float As[GBK][GBM + 4];
    __shared__ float Bs[GBK][GBN + 4];

    float acc[8][8];
#pragma unroll
    for (int i = 0; i < 8; ++i)
#pragma unroll
        for (int j = 0; j < 8; ++j) acc[i][j] = 0.0f;

    const int lr = tid >> 2;         // 0..63
    const int lk = (tid & 3) << 2;   // 0,4,8,12
    const int kb_n = tid >> 5;       // 0..7   (NN B-tile row)
    const int nb_n = (tid & 31) << 2;// 0..124 (NN B-tile col)

    float sa0 = 1.f, sa1 = 1.f, sb0 = 1.f, sb1 = 1.f;
    if (rsA) {
        sa0 = rsA[(size_t)z * M + bm + lr];
        sa1 = rsA[(size_t)z * M + bm + lr + 64];
    }
    if (TRANSB && rsB) {
        sb0 = rsB[(size_t)z * N + bn + lr];
        sb1 = rsB[(size_t)z * N + bn + lr + 64];
    }

    float4 pa0, pa1, pb0, pb1;

    auto gload = [&](int kt) {
        const float* pA = A + (size_t)(bm + lr) * K + kt * GBK + lk;
        pa0 = *(const float4*)pA;
        pa1 = *(const float4*)(pA + (size_t)64 * K);
        if (TRANSB) {
            const float* pB = B + (size_t)(bn + lr) * K + kt * GBK + lk;
            pb0 = *(const float4*)pB;
            pb1 = *(const float4*)(pB + (size_t)64 * K);
        } else {
            const float* pB = B + (size_t)(kt * GBK + kb_n) * N + bn + nb_n;
            pb0 = *(const float4*)pB;
            pb1 = *(const float4*)(pB + (size_t)8 * N);
        }
    };
    auto sstore = [&]() {
        As[lk + 0][lr] = pa0.x * sa0; As[lk + 1][lr] = pa0.y * sa0;
        As[lk + 2][lr] = pa0.z * sa0; As[lk + 3][lr] = pa0.w * sa0;
        As[lk + 0][lr + 64] = pa1.x * sa1; As[lk + 1][lr + 64] = pa1.y * sa1;
        As[lk + 2][lr + 64] = pa1.z * sa1; As[lk + 3][lr + 64] = pa1.w * sa1;
        if (TRANSB) {
            Bs[lk + 0][lr] = pb0.x * sb0; Bs[lk + 1][lr] = pb0.y * sb0;
            Bs[lk + 2][lr] = pb0.z * sb0; Bs[lk + 3][lr] = pb0.w * sb0;
            Bs[lk + 0][lr + 64] = pb1.x * sb1; Bs[lk + 1][lr + 64] = pb1.y * sb1;
            Bs[lk + 2][lr + 64] = pb1.z * sb1; Bs[lk + 3][lr + 64] = pb1.w * sb1;
        } else {
            *(float4*)&Bs[kb_n][nb_n]     = pb0;
            *(float4*)&Bs[kb_n + 8][nb_n] = pb1;
        }
    };

    const int nkt = K / GBK;
    gload(0);
    sstore();
    __syncthreads();
    for (int kt = 0; kt < nkt; ++kt) {
        if (kt + 1 < nkt) gload(kt + 1);
#pragma unroll
        for (int k = 0; k < GBK; ++k) {
            float4 a0 = *(const float4*)&As[k][ty * 8];
            float4 a1 = *(const float4*)&As[k][ty * 8 + 4];
            float4 b0 = *(const float4*)&Bs[k][tx * 8];
            float4 b1 = *(const float4*)&Bs[k][tx * 8 + 4];
            float av[8] = {a0.x, a0.y, a0.z, a0.w, a1.x, a1.y, a1.z, a1.w};
            float bv[8] = {b0.x, b0.y, b0.z, b0.w, b1.x, b1.y, b1.z, b1.w};
#pragma unroll
            for (int i = 0; i < 8; ++i)
#pragma unroll
                for (int j = 0; j < 8; ++j)
                    acc[i][j] = fmaf(av[i], bv[j], acc[i][j]);
        }
        __syncthreads();
        if (kt + 1 < nkt) { sstore(); __syncthreads(); }
    }

    float bb[8];
#pragma unroll
    for (int j = 0; j < 8; ++j) bb[j] = bias ? bias[bn + tx * 8 + j] : 0.0f;
#pragma unroll
    for (int i = 0; i < 8; ++i) {
        const int row = bm + ty * 8 + i;
        float* cp = Cc + (size_t)row * N + bn + tx * 8;
        float4 o0 = make_float4(acc[i][0] + bb[0], acc[i][1] + bb[1],
                                acc[i][2] + bb[2], acc[i][3] + bb[3]);
        float4 o1 = make_float4(acc[i][4] + bb[4], acc[i][5] + bb[5],
                                acc[i][6] + bb[6], acc[i][7] + bb[7]);
        *(float4*)cp = o0;
        *(float4*)(cp + 4) = o1;
    }
}

// ---------------- combined GRU input bias: bcomb = bih + Wih @ b_proj --------------
__global__ void bias_combine(const float* __restrict__ Wih, const float* __restrict__ b_proj,
                             const float* __restrict__ bih, float* __restrict__ bcomb)
{
    const int j = blockIdx.x * blockDim.x + threadIdx.x;
    if (j >= 768) return;
    float s = bih[j];
    for (int k = 0; k < 512; ++k) s = fmaf(Wih[(size_t)j * 512 + k], b_proj[k], s);
    bcomb[j] = s;
}

// ---------------- GRU scan: persistent blocks, h in LDS, Whh streamed -------------
// grid: mode==0 -> 128 blocks (both dirs), mode==1 -> 64 blocks fwd, mode==2 -> 64 bwd
// each block: 256 threads, G=4 batches. thread j owns rows j, j+256, j+512 of Whh.
__global__ __launch_bounds__(256)
void gru_scan(const float* __restrict__ gi_f, const float* __restrict__ gi_b,
              const float* __restrict__ Whh_f, const float* __restrict__ Whh_b,
              const float* __restrict__ bhh_f, const float* __restrict__ bhh_b,
              float* __restrict__ H, int mode)
{
    int dir, grp;
    if (mode == 0) { dir = blockIdx.x >> 6; grp = blockIdx.x & 63; }
    else           { dir = mode - 1;        grp = blockIdx.x; }
    const float* gi  = dir ? gi_b  : gi_f;
    const float* Whh = dir ? Whh_b : Whh_f;
    const float* bhh = dir ? bhh_b : bhh_f;

    const int j  = threadIdx.x;    // 0..255
    const int b0 = grp * 4;

    __shared__ float h[4][256];
#pragma unroll
    for (int g = 0; g < 4; ++g) h[g][j] = 0.0f;
    __syncthreads();

    const float bh_r = bhh[j], bh_z = bhh[j + 256], bh_n = bhh[j + 512];
    const float4* W4r = (const float4*)(Whh + (size_t)j * 256);
    const float4* W4z = (const float4*)(Whh + (size_t)(j + 256) * 256);
    const float4* W4n = (const float4*)(Whh + (size_t)(j + 512) * 256);

    for (int t = 0; t < 256; ++t) {
        const int tt = dir ? (255 - t) : t;

        // prefetch gi for all 4 batches (issue early, consumed after dots)
        float gir[4], giz[4], gin[4];
#pragma unroll
        for (int g = 0; g < 4; ++g) {
            const size_t gib = ((size_t)(b0 + g) * 256 + tt) * 768;
            gir[g] = gi[gib + j];
            giz[g] = gi[gib + 256 + j];
            gin[g] = gi[gib + 512 + j];
        }

        float ar[4] = {0,0,0,0}, az[4] = {0,0,0,0}, an[4] = {0,0,0,0};
#pragma unroll 4
        for (int kc = 0; kc < 64; ++kc) {
            float4 wr = W4r[kc];
            float4 wz = W4z[kc];
            float4 wn = W4n[kc];
#pragma unroll
            for (int g = 0; g < 4; ++g) {
                float4 hv = *(const float4*)&h[g][kc << 2];
                ar[g] = fmaf(wr.x, hv.x, ar[g]); ar[g] = fmaf(wr.y, hv.y, ar[g]);
                ar[g] = fmaf(wr.z, hv.z, ar[g]); ar[g] = fmaf(wr.w, hv.w, ar[g]);
                az[g] = fmaf(wz.x, hv.x, az[g]); az[g] = fmaf(wz.y, hv.y, az[g]);
                az[g] = fmaf(wz.z, hv.z, az[g]); az[g] = fmaf(wz.w, hv.w, az[g]);
                an[g] = fmaf(wn.x, hv.x, an[g]); an[g] = fmaf(wn.y, hv.y, an[g]);
                an[g] = fmaf(wn.z, hv.z, an[g]); an[g] = fmaf(wn.w, hv.w, an[g]);
            }
        }

        float hnew[4];
#pragma unroll
        for (int g = 0; g < 4; ++g) {
            float r  = 1.0f / (1.0f + expf(-(gir[g] + ar[g] + bh_r)));
            float zz = 1.0f / (1.0f + expf(-(giz[g] + az[g] + bh_z)));
            float nn = tanhf(gin[g] + r * (an[g] + bh_n));
            hnew[g] = (1.0f - zz) * nn + zz * h[g][j];
        }
        __syncthreads();
#pragma unroll
        for (int g = 0; g < 4; ++g) {
            h[g][j] = hnew[g];
            H[((size_t)(b0 + g) * 256 + tt) * 512 + dir * 256 + j] = hnew[g];
        }
        __syncthreads();
    }
}

// ---------------- row 1/max(norm,1e-12) for cosine normalization ------------------
__global__ __launch_bounds__(256)
void rownorm(const float* __restrict__ H, float* __restrict__ rinv)
{
    const int row  = blockIdx.x * 4 + (threadIdx.x >> 6);
    const int lane = threadIdx.x & 63;
    const float4* p = (const float4*)(H + (size_t)row * 512);
    float ss = 0.f;
    float4 v = p[lane];
    ss += v.x * v.x + v.y * v.y + v.z * v.z + v.w * v.w;
    v = p[lane + 64];
    ss += v.x * v.x + v.y * v.y + v.z * v.z + v.w * v.w;
#pragma unroll
    for (int off = 32; off >= 1; off >>= 1) ss += __shfl_xor(ss, off);
    if (lane == 0) rinv[row] = 1.0f / fmaxf(sqrtf(ss), 1e-12f);
}

// ---------------- top-5 per sim row (strict >, jax lower-index tie behavior) ------
__global__ __launch_bounds__(256)
void topk5(const float* __restrict__ sim, int* __restrict__ idx)
{
    const int row = blockIdx.x * 256 + threadIdx.x;
    const float* p = sim + (size_t)row * 256;
    float bv0 = -1e30f, bv1 = -1e30f, bv2 = -1e30f, bv3 = -1e30f, bv4 = -1e30f;
    int   bi0 = 0, bi1 = 0, bi2 = 0, bi3 = 0, bi4 = 0;
    for (int m4 = 0; m4 < 64; ++m4) {
        float4 v4 = *(const float4*)(p + m4 * 4);
        float vv[4] = {v4.x, v4.y, v4.z, v4.w};
#pragma unroll
        for (int c = 0; c < 4; ++c) {
            float v = vv[c];
            int   m = m4 * 4 + c;
            if (v > bv0) {
                if (v > bv1) {
                    bv0 = bv1; bi0 = bi1;
                    if (v > bv2) {
                        bv1 = bv2; bi1 = bi2;
                        if (v > bv3) {
                            bv2 = bv3; bi2 = bi3;
                            if (v > bv4) { bv3 = bv4; bi3 = bi4; bv4 = v; bi4 = m; }
                            else         { bv3 = v;  bi3 = m; }
                        } else { bv2 = v; bi2 = m; }
                    } else { bv1 = v; bi1 = m; }
                } else { bv0 = v; bi0 = m; }
            }
        }
    }
    int* o = idx + (size_t)row * 5;
    o[0] = bi0; o[1] = bi1; o[2] = bi2; o[3] = bi3; o[4] = bi4;
}

// ---------------- sparse GCN aggregation: out[n] = c*(X[n] + sum_j X[idx_j]) ------
template<bool RELU, int DIM>
__global__ __launch_bounds__(128)
void gcn_agg(const float* __restrict__ X, const int* __restrict__ idxs,
             float* __restrict__ outp, float cnorm)
{
    const int row = blockIdx.x;          // b*256 + n
    const int bbase = row & ~255;        // b*256
    const int* id = idxs + (size_t)row * 5;
    const int i0 = bbase + id[0];
    const int i1 = bbase + id[1];
    const int i2 = bbase + id[2];
    const int i3 = bbase + id[3];
    const int i4 = bbase + id[4];
    const int t = threadIdx.x;
    if (DIM == 512) {
        const float4* Xp = (const float4*)X;
        float4 a = Xp[(size_t)row * 128 + t];
        float4 v;
        v = Xp[(size_t)i0 * 128 + t]; a.x += v.x; a.y += v.y; a.z += v.z; a.w += v.w;
        v = Xp[(size_t)i1 * 128 + t]; a.x += v.x; a.y += v.y; a.z += v.z; a.w += v.w;
        v = Xp[(size_t)i2 * 128 + t]; a.x += v.x; a.y += v.y; a.z += v.z; a.w += v.w;
        v = Xp[(size_t)i3 * 128 + t]; a.x += v.x; a.y += v.y; a.z += v.z; a.w += v.w;
        v = Xp[(size_t)i4 * 128 + t]; a.x += v.x; a.y += v.y; a.z += v.z; a.w += v.w;
        a.x *= cnorm; a.y *= cnorm; a.z *= cnorm; a.w *= cnorm;
        if (RELU) {
            a.x = fmaxf(a.x, 0.f); a.y = fmaxf(a.y, 0.f);
            a.z = fmaxf(a.z, 0.f); a.w = fmaxf(a.w, 0.f);
        }
        ((float4*)outp)[(size_t)row * 128 + t] = a;
    } else {
        float a = X[(size_t)row * 128 + t];
        a += X[(size_t)i0 * 128 + t];
        a += X[(size_t)i1 * 128 + t];
        a += X[(size_t)i2 * 128 + t];
        a += X[(size_t)i3 * 128 + t];
        a += X[(size_t)i4 * 128 + t];
        a *= cnorm;
        if (RELU) a = fmaxf(a, 0.f);
        outp[(size_t)row * 128 + t] = a;
    }
}

// ------------------------------- launcher -----------------------------------------
extern "C" void kernel_launch(void* const* d_in, const int* in_sizes, int n_in,
                              void* d_out, int out_size, void* d_ws, size_t ws_size,
                              hipStream_t stream)
{
    (void)in_sizes; (void)n_in; (void)out_size;

    const float* C_masked = (const float*)d_in[0];
    const float* W_proj   = (const float*)d_in[1];
    const float* b_proj   = (const float*)d_in[2];
    const float* Wih_f    = (const float*)d_in[3];
    const float* Whh_f    = (const float*)d_in[4];
    const float* bih_f    = (const float*)d_in[5];
    const float* bhh_f    = (const float*)d_in[6];
    const float* Wih_b    = (const float*)d_in[7];
    const float* Whh_b    = (const float*)d_in[8];
    const float* bih_b    = (const float*)d_in[9];
    const float* bhh_b    = (const float*)d_in[10];
    const float* W_gcn1   = (const float*)d_in[11];
    const float* W_gcn2   = (const float*)d_in[12];
    float* out = (float*)d_out;

    char* ws = (char*)d_ws;
    size_t o = 0;
    auto take = [&](size_t bytes) {
        size_t r = o;
        o = (o + bytes + 255) & ~(size_t)255;
        return r;
    };
    const size_t o_wcf  = take((size_t)768 * 256 * 4);
    const size_t o_wcb  = take((size_t)768 * 256 * 4);
    const size_t o_bcf  = take(768 * 4);
    const size_t o_bcb  = take(768 * 4);
    const size_t o_rinv = take((size_t)65536 * 4);
    const size_t o_topk = take((size_t)65536 * 5 * 4);
    const size_t regionA = o;

    const size_t GI_BYTES = (size_t)65536 * 768 * 4;   // 201,326,592
    const size_t H_BYTES  = (size_t)65536 * 512 * 4;   // 134,217,728
    const size_t need_par = regionA + 2 * GI_BYTES + H_BYTES;
    const bool par = (ws_size >= need_par);

    float* wcomb_f = (float*)(ws + o_wcf);
    float* wcomb_b = (float*)(ws + o_wcb);
    float* bcomb_f = (float*)(ws + o_bcf);
    float* bcomb_b = (float*)(ws + o_bcb);
    float* rinv    = (float*)(ws + o_rinv);
    int*   topk    = (int*)(ws + o_topk);

    float* gi_f = (float*)(ws + regionA);
    float* gi_b = par ? (float*)(ws + regionA + GI_BYTES) : gi_f;
    float* Hbuf = (float*)(ws + regionA + (par ? 2 * GI_BYTES : GI_BYTES));

    // post-scan reuse of gi region (offsets valid for both modes)
    float* sim  = (float*)(ws + regionA);               // 67,108,864 B
    float* XW1  = (float*)(ws + regionA + 67108864);    // 33,554,432 B
    float* Z1   = (float*)(ws + regionA + 167772160);   // 33,554,432 B
    float* Z1W2 = (float*)(ws + regionA);               // 134,217,728 B (sim+XW1 dead)

    const dim3 blk(256);

    // 1. combined weights + biases
    gemm_f32<false><<<dim3(2, 6, 1), blk, 0, stream>>>(
        768, 256, 512, Wih_f, 0, W_proj, 0, wcomb_f, 0, nullptr, nullptr, nullptr);
    gemm_f32<false><<<dim3(2, 6, 1), blk, 0, stream>>>(
        768, 256, 512, Wih_b, 0, W_proj, 0, wcomb_b, 0, nullptr, nullptr, nullptr);
    bias_combine<<<3, 256, 0, stream>>>(Wih_f, b_proj, bih_f, bcomb_f);
    bias_combine<<<3, 256, 0, stream>>>(Wih_b, b_proj, bih_b, bcomb_b);

    // 2. gi GEMMs + GRU scans
    if (par) {
        gemm_f32<true><<<dim3(6, 512, 1), blk, 0, stream>>>(
            65536, 768, 256, C_masked, 0, wcomb_f, 0, gi_f, 0, bcomb_f, nullptr, nullptr);
        gemm_f32<true><<<dim3(6, 512, 1), blk, 0, stream>>>(
            65536, 768, 256, C_masked, 0, wcomb_b, 0, gi_b, 0, bcomb_b, nullptr, nullptr);
        gru_scan<<<128, blk, 0, stream>>>(gi_f, gi_b, Whh_f, Whh_b, bhh_f, bhh_b, Hbuf, 0);
    } else {
        gemm_f32<true><<<dim3(6, 512, 1), blk, 0, stream>>>(
            65536, 768, 256, C_masked, 0, wcomb_f, 0, gi_f, 0, bcomb_f, nullptr, nullptr);
        gru_scan<<<64, blk, 0, stream>>>(gi_f, gi_f, Whh_f, Whh_b, bhh_f, bhh_b, Hbuf, 1);
        gemm_f32<true><<<dim3(6, 512, 1), blk, 0, stream>>>(
            65536, 768, 256, C_masked, 0, wcomb_b, 0, gi_f, 0, bcomb_b, nullptr, nullptr);
        gru_scan<<<64, blk, 0, stream>>>(gi_f, gi_f, Whh_f, Whh_b, bhh_f, bhh_b, Hbuf, 2);
    }

    // 3. cosine-sim -> top-5
    rownorm<<<16384, blk, 0, stream>>>(Hbuf, rinv);
    gemm_f32<true><<<dim3(2, 2, 256), blk, 0, stream>>>(
        256, 256, 512, Hbuf, (long long)256 * 512, Hbuf, (long long)256 * 512,
        sim, (long long)256 * 256, nullptr, rinv, rinv);
    topk5<<<256, blk, 0, stream>>>(sim, topk);

    // 4. GCN with A_norm = A / (6 + 1e-8)  (row-sum of A is always K+1 = 6)
    const float cnorm = (float)(1.0 / (6.0 + 1e-8));
    gemm_f32<false><<<dim3(1, 512, 1), blk, 0, stream>>>(
        65536, 128, 512, Hbuf, 0, W_gcn1, 0, XW1, 0, nullptr, nullptr, nullptr);
    gcn_agg<true, 128><<<65536, 128, 0, stream>>>(XW1, topk, Z1, cnorm);
    gemm_f32<false><<<dim3(4, 512, 1), blk, 0, stream>>>(
        65536, 512, 128, Z1, 0, W_gcn2, 0, Z1W2, 0, nullptr, nullptr, nullptr);
    gcn_agg<false, 512><<<65536, 128, 0, stream>>>(Z1W2, topk, out, cnorm);
}

// Round 2
// 9970.618 us; speedup vs baseline: 1.4316x; 1.4316x over previous
//
#include <hip/hip_runtime.h>
#include <cstdint>
#include <cmath>

// ---------------- fp32 tiled GEMM: C = A @ B (+bias, optional per-row scaling) ----
// A: M x K row-major.  B: TRANSB ? (N x K) : (K x N) row-major.
// batched via blockIdx.z with element strides sA, sB, sC.
// rsA/rsB: optional per-row scale factors (used for cosine-sim normalization).
#define GBM 128
#define GBN 128
#define GBK 16

template<bool TRANSB>
__global__ __launch_bounds__(256)
void gemm_f32(int M, int N, int K,
              const float* __restrict__ A, long long sA,
              const float* __restrict__ B, long long sB,
              float* __restrict__ Cc, long long sC,
              const float* __restrict__ bias,
              const float* __restrict__ rsA,
              const float* __restrict__ rsB)
{
    const int z = blockIdx.z;
    A  += (size_t)z * (size_t)sA;
    B  += (size_t)z * (size_t)sB;
    Cc += (size_t)z * (size_t)sC;

    const int bm = blockIdx.y * GBM;
    const int bn = blockIdx.x * GBN;
    const int tid = threadIdx.x;
    const int tx = tid & 15;
    const int ty = tid >> 4;

    __shared__ float As[GBK][GBM + 4];
    __shared__ float Bs[GBK][GBN + 4];

    float acc[8][8];
#pragma unroll
    for (int i = 0; i < 8; ++i)
#pragma unroll
        for (int j = 0; j < 8; ++j) acc[i][j] = 0.0f;

    const int lr = tid >> 2;         // 0..63
    const int lk = (tid & 3) << 2;   // 0,4,8,12
    const int kb_n = tid >> 5;       // 0..7   (NN B-tile row)
    const int nb_n = (tid & 31) << 2;// 0..124 (NN B-tile col)

    float sa0 = 1.f, sa1 = 1.f, sb0 = 1.f, sb1 = 1.f;
    if (rsA) {
        sa0 = rsA[(size_t)z * M + bm + lr];
        sa1 = rsA[(size_t)z * M + bm + lr + 64];
    }
    if (TRANSB && rsB) {
        sb0 = rsB[(size_t)z * N + bn + lr];
        sb1 = rsB[(size_t)z * N + bn + lr + 64];
    }

    float4 pa0, pa1, pb0, pb1;

    auto gload = [&](int kt) {
        const float* pA = A + (size_t)(bm + lr) * K + kt * GBK + lk;
        pa0 = *(const float4*)pA;
        pa1 = *(const float4*)(pA + (size_t)64 * K);
        if (TRANSB) {
            const float* pB = B + (size_t)(bn + lr) * K + kt * GBK + lk;
            pb0 = *(const float4*)pB;
            pb1 = *(const float4*)(pB + (size_t)64 * K);
        } else {
            const float* pB = B + (size_t)(kt * GBK + kb_n) * N + bn + nb_n;
            pb0 = *(const float4*)pB;
            pb1 = *(const float4*)(pB + (size_t)8 * N);
        }
    };
    auto sstore = [&]() {
        As[lk + 0][lr] = pa0.x * sa0; As[lk + 1][lr] = pa0.y * sa0;
        As[lk + 2][lr] = pa0.z * sa0; As[lk + 3][lr] = pa0.w * sa0;
        As[lk + 0][lr + 64] = pa1.x * sa1; As[lk + 1][lr + 64] = pa1.y * sa1;
        As[lk + 2][lr + 64] = pa1.z * sa1; As[lk + 3][lr + 64] = pa1.w * sa1;
        if (TRANSB) {
            Bs[lk + 0][lr] = pb0.x * sb0; Bs[lk + 1][lr] = pb0.y * sb0;
            Bs[lk + 2][lr] = pb0.z * sb0; Bs[lk + 3][lr] = pb0.w * sb0;
            Bs[lk + 0][lr + 64] = pb1.x * sb1; Bs[lk + 1][lr + 64] = pb1.y * sb1;
            Bs[lk + 2][lr + 64] = pb1.z * sb1; Bs[lk + 3][lr + 64] = pb1.w * sb1;
        } else {
            *(float4*)&Bs[kb_n][nb_n]     = pb0;
            *(float4*)&Bs[kb_n + 8][nb_n] = pb1;
        }
    };

    const int nkt = K / GBK;
    gload(0);
    sstore();
    __syncthreads();
    for (int kt = 0; kt < nkt; ++kt) {
        if (kt + 1 < nkt) gload(kt + 1);
#pragma unroll
        for (int k = 0; k < GBK; ++k) {
            float4 a0 = *(const float4*)&As[k][ty * 8];
            float4 a1 = *(const float4*)&As[k][ty * 8 + 4];
            float4 b0 = *(const float4*)&Bs[k][tx * 8];
            float4 b1 = *(const float4*)&Bs[k][tx * 8 + 4];
            float av[8] = {a0.x, a0.y, a0.z, a0.w, a1.x, a1.y, a1.z, a1.w};
            float bv[8] = {b0.x, b0.y, b0.z, b0.w, b1.x, b1.y, b1.z, b1.w};
#pragma unroll
            for (int i = 0; i < 8; ++i)
#pragma unroll
                for (int j = 0; j < 8; ++j)
                    acc[i][j] = fmaf(av[i], bv[j], acc[i][j]);
        }
        __syncthreads();
        if (kt + 1 < nkt) { sstore(); __syncthreads(); }
    }

    float bb[8];
#pragma unroll
    for (int j = 0; j < 8; ++j) bb[j] = bias ? bias[bn + tx * 8 + j] : 0.0f;
#pragma unroll
    for (int i = 0; i < 8; ++i) {
        const int row = bm + ty * 8 + i;
        float* cp = Cc + (size_t)row * N + bn + tx * 8;
        float4 o0 = make_float4(acc[i][0] + bb[0], acc[i][1] + bb[1],
                                acc[i][2] + bb[2], acc[i][3] + bb[3]);
        float4 o1 = make_float4(acc[i][4] + bb[4], acc[i][5] + bb[5],
                                acc[i][6] + bb[6], acc[i][7] + bb[7]);
        *(float4*)cp = o0;
        *(float4*)(cp + 4) = o1;
    }
}

// ---------------- combined GRU input bias: bcomb = bih + Wih @ b_proj --------------
__global__ void bias_combine(const float* __restrict__ Wih, const float* __restrict__ b_proj,
                             const float* __restrict__ bih, float* __restrict__ bcomb)
{
    const int j = blockIdx.x * blockDim.x + threadIdx.x;
    if (j >= 768) return;
    float s = bih[j];
    for (int k = 0; k < 512; ++k) s = fmaf(Wih[(size_t)j * 512 + k], b_proj[k], s);
    bcomb[j] = s;
}

// ---------------- GRU scan v2: 1024 threads, G=2 batches, 16 waves/CU --------------
// Thread (j = tid>>2, q = tid&3) computes partial dot (k in [q*64, q*64+64)) of
// Whh rows {j, j+256, j+512} against h for 2 batches; 2x shfl_xor reduces over q;
// lanes q<2 run the activation for batch g=q. h ping-pongs in LDS with quarter
// padding (stride 68) so the 4 q-groups hit disjoint banks. One barrier/step.
// Weight addresses are loop-invariant: compiler hoists what fits under the
// 128-VGPR cap (free partial weight residency), streams the rest from L2.
__global__ __launch_bounds__(1024)
void gru_scan(const float* __restrict__ gi_f, const float* __restrict__ gi_b,
              const float* __restrict__ Whh_f, const float* __restrict__ Whh_b,
              const float* __restrict__ bhh_f, const float* __restrict__ bhh_b,
              float* __restrict__ H, int mode)
{
    int dir, grp;
    if (mode == 0) { dir = blockIdx.x >> 7; grp = blockIdx.x & 127; }
    else           { dir = mode - 1;        grp = blockIdx.x; }
    const float* __restrict__ gi  = dir ? gi_b  : gi_f;
    const float* __restrict__ Whh = dir ? Whh_b : Whh_f;
    const float* __restrict__ bhh = dir ? bhh_b : bhh_f;
    const int b0 = grp * 2;

    const int tid = threadIdx.x;
    const int j = tid >> 2;    // unit 0..255
    const int q = tid & 3;     // k-quarter

    __shared__ float hb[2][2][272];   // [pingpong][batch][padded 4x68]
    for (int i = tid; i < 1088; i += 1024) ((float*)hb)[i] = 0.0f;
    __syncthreads();

    const float4* __restrict__ Wr = (const float4*)(Whh + (size_t)j * 256 + q * 64);
    const float4* __restrict__ Wz = (const float4*)(Whh + (size_t)(j + 256) * 256 + q * 64);
    const float4* __restrict__ Wn = (const float4*)(Whh + (size_t)(j + 512) * 256 + q * 64);

    float bh_r = 0.f, bh_z = 0.f, bh_n = 0.f;
    if (q < 2) { bh_r = bhh[j]; bh_z = bhh[j + 256]; bh_n = bhh[j + 512]; }

    const int hsel = (j >> 6) * 68 + (j & 63);   // LDS slot of unit j

    int p = 0;
    for (int t = 0; t < 256; ++t) {
        const int tt = dir ? (255 - t) : t;

        float gr = 0.f, gz = 0.f, gn = 0.f;
        if (q < 2) {
            const size_t gib = ((size_t)(b0 + q) * 256 + tt) * 768;
            gr = gi[gib + j];
            gz = gi[gib + 256 + j];
            gn = gi[gib + 512 + j];
        }

        const float* h0 = &hb[p][0][q * 68];
        const float* h1 = &hb[p][1][q * 68];

        float ar0 = 0.f, az0 = 0.f, an0 = 0.f;
        float ar1 = 0.f, az1 = 0.f, an1 = 0.f;
#pragma unroll
        for (int kk = 0; kk < 16; ++kk) {
            const float4 wr = Wr[kk];
            const float4 wz = Wz[kk];
            const float4 wn = Wn[kk];
            const float4 a = *(const float4*)(h0 + kk * 4);
            const float4 b = *(const float4*)(h1 + kk * 4);
            ar0 = fmaf(wr.x, a.x, ar0); ar0 = fmaf(wr.y, a.y, ar0);
            ar0 = fmaf(wr.z, a.z, ar0); ar0 = fmaf(wr.w, a.w, ar0);
            az0 = fmaf(wz.x, a.x, az0); az0 = fmaf(wz.y, a.y, az0);
            az0 = fmaf(wz.z, a.z, az0); az0 = fmaf(wz.w, a.w, az0);
            an0 = fmaf(wn.x, a.x, an0); an0 = fmaf(wn.y, a.y, an0);
            an0 = fmaf(wn.z, a.z, an0); an0 = fmaf(wn.w, a.w, an0);
            ar1 = fmaf(wr.x, b.x, ar1); ar1 = fmaf(wr.y, b.y, ar1);
            ar1 = fmaf(wr.z, b.z, ar1); ar1 = fmaf(wr.w, b.w, ar1);
            az1 = fmaf(wz.x, b.x, az1); az1 = fmaf(wz.y, b.y, az1);
            az1 = fmaf(wz.z, b.z, az1); az1 = fmaf(wz.w, b.w, az1);
            an1 = fmaf(wn.x, b.x, an1); an1 = fmaf(wn.y, b.y, an1);
            an1 = fmaf(wn.z, b.z, an1); an1 = fmaf(wn.w, b.w, an1);
        }

        // reduce the 4 k-quarters (adjacent lanes)
        ar0 += __shfl_xor(ar0, 1); ar0 += __shfl_xor(ar0, 2);
        az0 += __shfl_xor(az0, 1); az0 += __shfl_xor(az0, 2);
        an0 += __shfl_xor(an0, 1); an0 += __shfl_xor(an0, 2);
        ar1 += __shfl_xor(ar1, 1); ar1 += __shfl_xor(ar1, 2);
        az1 += __shfl_xor(az1, 1); az1 += __shfl_xor(az1, 2);
        an1 += __shfl_xor(an1, 1); an1 += __shfl_xor(an1, 2);

        if (q < 2) {
            const float ar = q ? ar1 : ar0;
            const float az = q ? az1 : az0;
            const float an = q ? an1 : an0;
            const float r  = 1.0f / (1.0f + expf(-(gr + ar + bh_r)));
            const float zz = 1.0f / (1.0f + expf(-(gz + az + bh_z)));
            const float nn = tanhf(gn + r * (an + bh_n));
            const float hold = hb[p][q][hsel];
            const float hnew = (1.0f - zz) * nn + zz * hold;
            hb[p ^ 1][q][hsel] = hnew;
            H[((size_t)(b0 + q) * 256 + tt) * 512 + dir * 256 + j] = hnew;
        }
        __syncthreads();
        p ^= 1;
    }
}

// ---------------- row 1/max(norm,1e-12) for cosine normalization ------------------
__global__ __launch_bounds__(256)
void rownorm(const float* __restrict__ H, float* __restrict__ rinv)
{
    const int row  = blockIdx.x * 4 + (threadIdx.x >> 6);
    const int lane = threadIdx.x & 63;
    const float4* p = (const float4*)(H + (size_t)row * 512);
    float ss = 0.f;
    float4 v = p[lane];
    ss += v.x * v.x + v.y * v.y + v.z * v.z + v.w * v.w;
    v = p[lane + 64];
    ss += v.x * v.x + v.y * v.y + v.z * v.z + v.w * v.w;
#pragma unroll
    for (int off = 32; off >= 1; off >>= 1) ss += __shfl_xor(ss, off);
    if (lane == 0) rinv[row] = 1.0f / fmaxf(sqrtf(ss), 1e-12f);
}

// ---------------- top-5 per sim row (strict >, jax lower-index tie behavior) ------
__global__ __launch_bounds__(256)
void topk5(const float* __restrict__ sim, int* __restrict__ idx)
{
    const int row = blockIdx.x * 256 + threadIdx.x;
    const float* p = sim + (size_t)row * 256;
    float bv0 = -1e30f, bv1 = -1e30f, bv2 = -1e30f, bv3 = -1e30f, bv4 = -1e30f;
    int   bi0 = 0, bi1 = 0, bi2 = 0, bi3 = 0, bi4 = 0;
    for (int m4 = 0; m4 < 64; ++m4) {
        float4 v4 = *(const float4*)(p + m4 * 4);
        float vv[4] = {v4.x, v4.y, v4.z, v4.w};
#pragma unroll
        for (int c = 0; c < 4; ++c) {
            float v = vv[c];
            int   m = m4 * 4 + c;
            if (v > bv0) {
                if (v > bv1) {
                    bv0 = bv1; bi0 = bi1;
                    if (v > bv2) {
                        bv1 = bv2; bi1 = bi2;
                        if (v > bv3) {
                            bv2 = bv3; bi2 = bi3;
                            if (v > bv4) { bv3 = bv4; bi3 = bi4; bv4 = v; bi4 = m; }
                            else         { bv3 = v;  bi3 = m; }
                        } else { bv2 = v; bi2 = m; }
                    } else { bv1 = v; bi1 = m; }
                } else { bv0 = v; bi0 = m; }
            }
        }
    }
    int* o = idx + (size_t)row * 5;
    o[0] = bi0; o[1] = bi1; o[2] = bi2; o[3] = bi3; o[4] = bi4;
}

// ---------------- sparse GCN aggregation: out[n] = c*(X[n] + sum_j X[idx_j]) ------
template<bool RELU, int DIM>
__global__ __launch_bounds__(128)
void gcn_agg(const float* __restrict__ X, const int* __restrict__ idxs,
             float* __restrict__ outp, float cnorm)
{
    const int row = blockIdx.x;          // b*256 + n
    const int bbase = row & ~255;        // b*256
    const int* id = idxs + (size_t)row * 5;
    const int i0 = bbase + id[0];
    const int i1 = bbase + id[1];
    const int i2 = bbase + id[2];
    const int i3 = bbase + id[3];
    const int i4 = bbase + id[4];
    const int t = threadIdx.x;
    if (DIM == 512) {
        const float4* Xp = (const float4*)X;
        float4 a = Xp[(size_t)row * 128 + t];
        float4 v;
        v = Xp[(size_t)i0 * 128 + t]; a.x += v.x; a.y += v.y; a.z += v.z; a.w += v.w;
        v = Xp[(size_t)i1 * 128 + t]; a.x += v.x; a.y += v.y; a.z += v.z; a.w += v.w;
        v = Xp[(size_t)i2 * 128 + t]; a.x += v.x; a.y += v.y; a.z += v.z; a.w += v.w;
        v = Xp[(size_t)i3 * 128 + t]; a.x += v.x; a.y += v.y; a.z += v.z; a.w += v.w;
        v = Xp[(size_t)i4 * 128 + t]; a.x += v.x; a.y += v.y; a.z += v.z; a.w += v.w;
        a.x *= cnorm; a.y *= cnorm; a.z *= cnorm; a.w *= cnorm;
        if (RELU) {
            a.x = fmaxf(a.x, 0.f); a.y = fmaxf(a.y, 0.f);
            a.z = fmaxf(a.z, 0.f); a.w = fmaxf(a.w, 0.f);
        }
        ((float4*)outp)[(size_t)row * 128 + t] = a;
    } else {
        float a = X[(size_t)row * 128 + t];
        a += X[(size_t)i0 * 128 + t];
        a += X[(size_t)i1 * 128 + t];
        a += X[(size_t)i2 * 128 + t];
        a += X[(size_t)i3 * 128 + t];
        a += X[(size_t)i4 * 128 + t];
        a *= cnorm;
        if (RELU) a = fmaxf(a, 0.f);
        outp[(size_t)row * 128 + t] = a;
    }
}

// ------------------------------- launcher -----------------------------------------
extern "C" void kernel_launch(void* const* d_in, const int* in_sizes, int n_in,
                              void* d_out, int out_size, void* d_ws, size_t ws_size,
                              hipStream_t stream)
{
    (void)in_sizes; (void)n_in; (void)out_size;

    const float* C_masked = (const float*)d_in[0];
    const float* W_proj   = (const float*)d_in[1];
    const float* b_proj   = (const float*)d_in[2];
    const float* Wih_f    = (const float*)d_in[3];
    const float* Whh_f    = (const float*)d_in[4];
    const float* bih_f    = (const float*)d_in[5];
    const float* bhh_f    = (const float*)d_in[6];
    const float* Wih_b    = (const float*)d_in[7];
    const float* Whh_b    = (const float*)d_in[8];
    const float* bih_b    = (const float*)d_in[9];
    const float* bhh_b    = (const float*)d_in[10];
    const float* W_gcn1   = (const float*)d_in[11];
    const float* W_gcn2   = (const float*)d_in[12];
    float* out = (float*)d_out;

    char* ws = (char*)d_ws;
    size_t o = 0;
    auto take = [&](size_t bytes) {
        size_t r = o;
        o = (o + bytes + 255) & ~(size_t)255;
        return r;
    };
    const size_t o_wcf  = take((size_t)768 * 256 * 4);
    const size_t o_wcb  = take((size_t)768 * 256 * 4);
    const size_t o_bcf  = take(768 * 4);
    const size_t o_bcb  = take(768 * 4);
    const size_t o_rinv = take((size_t)65536 * 4);
    const size_t o_topk = take((size_t)65536 * 5 * 4);
    const size_t regionA = o;

    const size_t GI_BYTES = (size_t)65536 * 768 * 4;   // 201,326,592
    const size_t H_BYTES  = (size_t)65536 * 512 * 4;   // 134,217,728
    const size_t need_par = regionA + 2 * GI_BYTES + H_BYTES;
    const bool par = (ws_size >= need_par);

    float* wcomb_f = (float*)(ws + o_wcf);
    float* wcomb_b = (float*)(ws + o_wcb);
    float* bcomb_f = (float*)(ws + o_bcf);
    float* bcomb_b = (float*)(ws + o_bcb);
    float* rinv    = (float*)(ws + o_rinv);
    int*   topk    = (int*)(ws + o_topk);

    float* gi_f = (float*)(ws + regionA);
    float* gi_b = par ? (float*)(ws + regionA + GI_BYTES) : gi_f;
    float* Hbuf = (float*)(ws + regionA + (par ? 2 * GI_BYTES : GI_BYTES));

    // post-scan reuse of gi region (offsets valid for both modes)
    float* sim  = (float*)(ws + regionA);               // 67,108,864 B
    float* XW1  = (float*)(ws + regionA + 67108864);    // 33,554,432 B
    float* Z1   = (float*)(ws + regionA + 167772160);   // 33,554,432 B
    float* Z1W2 = (float*)(ws + regionA);               // 134,217,728 B (sim+XW1 dead)

    const dim3 blk(256);

    // 1. combined weights + biases
    gemm_f32<false><<<dim3(2, 6, 1), blk, 0, stream>>>(
        768, 256, 512, Wih_f, 0, W_proj, 0, wcomb_f, 0, nullptr, nullptr, nullptr);
    gemm_f32<false><<<dim3(2, 6, 1), blk, 0, stream>>>(
        768, 256, 512, Wih_b, 0, W_proj, 0, wcomb_b, 0, nullptr, nullptr, nullptr);
    bias_combine<<<3, 256, 0, stream>>>(Wih_f, b_proj, bih_f, bcomb_f);
    bias_combine<<<3, 256, 0, stream>>>(Wih_b, b_proj, bih_b, bcomb_b);

    // 2. gi GEMMs + GRU scans
    if (par) {
        gemm_f32<true><<<dim3(6, 512, 1), blk, 0, stream>>>(
            65536, 768, 256, C_masked, 0, wcomb_f, 0, gi_f, 0, bcomb_f, nullptr, nullptr);
        gemm_f32<true><<<dim3(6, 512, 1), blk, 0, stream>>>(
            65536, 768, 256, C_masked, 0, wcomb_b, 0, gi_b, 0, bcomb_b, nullptr, nullptr);
        gru_scan<<<256, dim3(1024), 0, stream>>>(gi_f, gi_b, Whh_f, Whh_b, bhh_f, bhh_b, Hbuf, 0);
    } else {
        gemm_f32<true><<<dim3(6, 512, 1), blk, 0, stream>>>(
            65536, 768, 256, C_masked, 0, wcomb_f, 0, gi_f, 0, bcomb_f, nullptr, nullptr);
        gru_scan<<<128, dim3(1024), 0, stream>>>(gi_f, gi_f, Whh_f, Whh_b, bhh_f, bhh_b, Hbuf, 1);
        gemm_f32<true><<<dim3(6, 512, 1), blk, 0, stream>>>(
            65536, 768, 256, C_masked, 0, wcomb_b, 0, gi_f, 0, bcomb_b, nullptr, nullptr);
        gru_scan<<<128, dim3(1024), 0, stream>>>(gi_f, gi_f, Whh_f, Whh_b, bhh_f, bhh_b, Hbuf, 2);
    }

    // 3. cosine-sim -> top-5
    rownorm<<<16384, blk, 0, stream>>>(Hbuf, rinv);
    gemm_f32<true><<<dim3(2, 2, 256), blk, 0, stream>>>(
        256, 256, 512, Hbuf, (long long)256 * 512, Hbuf, (long long)256 * 512,
        sim, (long long)256 * 256, nullptr, rinv, rinv);
    topk5<<<256, blk, 0, stream>>>(sim, topk);

    // 4. GCN with A_norm = A / (6 + 1e-8)  (row-sum of A is always K+1 = 6)
    const float cnorm = (float)(1.0 / (6.0 + 1e-8));
    gemm_f32<false><<<dim3(1, 512, 1), blk, 0, stream>>>(
        65536, 128, 512, Hbuf, 0, W_gcn1, 0, XW1, 0, nullptr, nullptr, nullptr);
    gcn_agg<true, 128><<<65536, 128, 0, stream>>>(XW1, topk, Z1, cnorm);
    gemm_f32<false><<<dim3(4, 512, 1), blk, 0, stream>>>(
        65536, 512, 128, Z1, 0, W_gcn2, 0, Z1W2, 0, nullptr, nullptr, nullptr);
    gcn_agg<false, 512><<<65536, 128, 0, stream>>>(Z1W2, topk, out, cnorm);
}